// Round 1
// baseline (1167.884 us; speedup 1.0000x reference)
//
#include <hip/hip_runtime.h>

// PoolHiddenNet: out[g][c] = max_{i in group g} relu( [hist_enc(i,:) || emb(i,:)] @ Wm[:,c] + bm[c] )
// emb(i,e) = relu( rel0*Ws[0][e] + rel1*Ws[1][e] + bs[e] ), rel = pos[i] - pos[start_of_group(i)]
//
// Round 0 baseline: fused fp32 tiled GEMM (64x64 tile, BK=16) + in-staging emb
// computation + block-level segment-max epilogue with int-punned atomicMax
// (valid since relu output >= 0 and out is memset to 0 each launch).

constexpr int Nrows  = 102400;
constexpr int NGROUP = 2048;   // seq_start_end has NGROUP+1 entries
constexpr int E      = 128;
constexpr int H      = 512;
constexpr int KDIM   = H + E;  // 640
constexpr int BM = 64, BN = 64, BK = 16;

__global__ __launch_bounds__(256) void pool_fused_kernel(
    const float* __restrict__ hist_enc,   // (N, H)
    const float* __restrict__ pos,        // (N, 2)
    const int*   __restrict__ sse,        // (NGROUP+1,)
    const float* __restrict__ Ws,         // (2, E)
    const float* __restrict__ bs,         // (E,)
    const float* __restrict__ Wm,         // (KDIM, H)
    const float* __restrict__ bm,         // (H,)
    float*       __restrict__ out)        // (NGROUP, H)
{
    __shared__ float At[BK][68];          // K-major A tile, pad 68 keeps float4 align + clean banks
    __shared__ float Bt[BK][BN];          // row stride 256B, 16B-aligned float4 rows
    __shared__ float Ps[BM][BN + 1];      // pooled tile for segment-max scan (pad 65: conflict-free column scan)
    __shared__ float relRow[BM][2];
    __shared__ int   segRow[BM];

    const int t       = threadIdx.x;
    const int cTile   = blockIdx.x * BN;
    const int rowBase = blockIdx.y * BM;

    // ---- prologue: per-row segment id (binary search) + rel position ----
    if (t < BM) {
        const int i = rowBase + t;
        // upper_bound(sse, i) - 1
        int l = 0, r = NGROUP + 1;
        while (l < r) { int m = (l + r) >> 1; if (sse[m] <= i) l = m + 1; else r = m; }
        const int g = l - 1;
        segRow[t] = g;
        const int a = sse[g];
        relRow[t][0] = pos[2 * i + 0] - pos[2 * a + 0];
        relRow[t][1] = pos[2 * i + 1] - pos[2 * a + 1];
    }
    __syncthreads();

    const int ty = t >> 4;        // 0..15 -> rows ty*4..ty*4+3
    const int tx = t & 15;        // 0..15 -> cols tx*4..tx*4+3

    // staging assignments
    const int ar  = t >> 2;         // 0..63   A row within tile
    const int aks = (t & 3) * 4;    // 0,4,8,12 A k-quad
    const int bkk = t >> 4;         // 0..15   B k row
    const int bc  = (t & 15) * 4;   // 0..60   B col quad

    float acc[4][4] = {};

    for (int kt = 0; kt < KDIM / BK; ++kt) {
        const int k0 = kt * BK;

        // ---- fetch next tiles (global) ----
        float4 av, bv;
        if (k0 < H) {
            av = *(const float4*)&hist_enc[(size_t)(rowBase + ar) * H + k0 + aks];
        } else {
            const float r0 = relRow[ar][0], r1 = relRow[ar][1];
            float tmp[4];
#pragma unroll
            for (int j = 0; j < 4; ++j) {
                const int e = k0 + aks + j - H;
                const float v = r0 * Ws[e] + r1 * Ws[E + e] + bs[e];
                tmp[j] = v > 0.0f ? v : 0.0f;
            }
            av = make_float4(tmp[0], tmp[1], tmp[2], tmp[3]);
        }
        bv = *(const float4*)&Wm[(size_t)(k0 + bkk) * H + cTile + bc];

        __syncthreads();   // previous tile's LDS reads complete

        At[aks + 0][ar] = av.x;
        At[aks + 1][ar] = av.y;
        At[aks + 2][ar] = av.z;
        At[aks + 3][ar] = av.w;
        *(float4*)&Bt[bkk][bc] = bv;

        __syncthreads();   // tiles visible

        // ---- compute ----
#pragma unroll
        for (int kk = 0; kk < BK; ++kk) {
            const float4 a4 = *(const float4*)&At[kk][ty * 4];
            const float4 b4 = *(const float4*)&Bt[kk][tx * 4];
            const float am[4] = {a4.x, a4.y, a4.z, a4.w};
            const float bn[4] = {b4.x, b4.y, b4.z, b4.w};
#pragma unroll
            for (int m = 0; m < 4; ++m)
#pragma unroll
                for (int n = 0; n < 4; ++n)
                    acc[m][n] += am[m] * bn[n];
        }
    }

    // ---- epilogue: bias + relu into Ps ----
    float bmv[4];
#pragma unroll
    for (int n = 0; n < 4; ++n) bmv[n] = bm[cTile + tx * 4 + n];
#pragma unroll
    for (int m = 0; m < 4; ++m) {
#pragma unroll
        for (int n = 0; n < 4; ++n) {
            float v = acc[m][n] + bmv[n];
            Ps[ty * 4 + m][tx * 4 + n] = v > 0.0f ? v : 0.0f;
        }
    }
    __syncthreads();

    // ---- block-level segment max scan (one thread per column; wave-uniform branches) ----
    if (t < BN) {
        const int c = t;
        float best = Ps[0][c];
        int   cur  = segRow[0];
        for (int r = 1; r < BM; ++r) {
            const int   g = segRow[r];
            const float v = Ps[r][c];
            if (g != cur) {
                atomicMax((int*)&out[(size_t)cur * H + cTile + c], __float_as_int(best));
                cur  = g;
                best = v;
            } else {
                best = fmaxf(best, v);
            }
        }
        atomicMax((int*)&out[(size_t)cur * H + cTile + c], __float_as_int(best));
    }
}

extern "C" void kernel_launch(void* const* d_in, const int* in_sizes, int n_in,
                              void* d_out, int out_size, void* d_ws, size_t ws_size,
                              hipStream_t stream) {
    const float* hist_enc = (const float*)d_in[0];
    const float* pos      = (const float*)d_in[1];
    const int*   sse      = (const int*)  d_in[2];
    const float* Ws       = (const float*)d_in[3];
    const float* bs       = (const float*)d_in[4];
    const float* Wm       = (const float*)d_in[5];
    const float* bm       = (const float*)d_in[6];
    float*       out      = (float*)d_out;

    // out is poisoned before every launch; segment-max accumulates via atomicMax
    // over non-negative values, so zero-init is required and correct.
    hipMemsetAsync(out, 0, (size_t)out_size * sizeof(float), stream);

    dim3 grid(H / BN, Nrows / BM);   // (8, 1600)
    pool_fused_kernel<<<grid, 256, 0, stream>>>(hist_enc, pos, sse, Ws, bs, Wm, bm, out);
}

// Round 2
// 555.078 us; speedup vs baseline: 2.1040x; 2.1040x over previous
//
#include <hip/hip_runtime.h>

// PoolHiddenNet round 2: bf16 MFMA GEMM (16x16x32), 128x128 tile, BK=32.
// A = [hist_enc || emb] converted fp32->bf16 in-register during LDS staging
// (emb computed on the fly for k>=512). Wm pre-transposed+converted to bf16
// in d_ws by a tiny pass-0 kernel (655 KB, L2-resident for the main pass).
// Segment-max epilogue: per-lane reduction over <=4 block-local segments ->
// LDS atomicMax -> global atomicMax (plain store when group fully inside block).

typedef __bf16 bf16x8 __attribute__((ext_vector_type(8)));
typedef float floatx4 __attribute__((ext_vector_type(4)));

constexpr int NR = 102400;
constexpr int NG = 2048;
constexpr int E  = 128;
constexpr int H  = 512;
constexpr int KD = 640;
constexpr int BM = 128, BN = 128, BK = 32;
constexpr int LDA = 40;   // ushort stride: 80 B rows -> 16B-aligned, 2-way-only bank aliasing

__device__ inline unsigned short f2bf(float f) {
    unsigned u = __float_as_uint(f);
    u += 0x7FFF + ((u >> 16) & 1u);   // RNE (inputs are finite/normal)
    return (unsigned short)(u >> 16);
}

// pass 0: WmT[n][k] = bf16(Wm[k][n]);  Wm is (640,512) fp32, WmT is (512,640) bf16
__global__ __launch_bounds__(256) void wm_transpose(const float* __restrict__ Wm,
                                                    unsigned short* __restrict__ WmT) {
    __shared__ float tile[64][65];
    const int kb = blockIdx.x * 64, nb = blockIdx.y * 64;
    const int tx = threadIdx.x & 63, tq = threadIdx.x >> 6;
#pragma unroll
    for (int i = 0; i < 16; ++i) {
        const int k = tq * 16 + i;
        tile[k][tx] = Wm[(size_t)(kb + k) * H + nb + tx];
    }
    __syncthreads();
#pragma unroll
    for (int i = 0; i < 16; ++i) {
        const int n = tq * 16 + i;
        WmT[(size_t)(nb + n) * KD + kb + tx] = f2bf(tile[tx][n]);
    }
}

__global__ __launch_bounds__(256) void pool_mfma(
    const float* __restrict__ hist_enc,       // (N, 512) fp32
    const float* __restrict__ pos,            // (N, 2)
    const int*   __restrict__ sse,            // (2049,)
    const float* __restrict__ Ws,             // (2, 128)
    const float* __restrict__ bs,             // (128,)
    const unsigned short* __restrict__ WmT,   // (512, 640) bf16
    const float* __restrict__ bm,             // (512,)
    float*       __restrict__ out)            // (2048, 512) fp32, zero-inited
{
    __shared__ __attribute__((aligned(16))) unsigned short As[BM][LDA];
    __shared__ __attribute__((aligned(16))) unsigned short Bs[BN][LDA];
    __shared__ float relRow[BM][2];
    __shared__ int   segRow[BM];
    __shared__ int   bnd[3];                 // local row idx of seg changes (128 = none)
    __shared__ int   Pmax[4][BN + 4];        // per-(localseg, col) max, int-punned (vals >= 0)

    const int t       = threadIdx.x;
    const int cTile   = blockIdx.x * BN;
    const int rowBase = blockIdx.y * BM;

    // ---- prologue ----
    if (t < BM) {
        const int i = rowBase + t;
        int l = 0, r = NG + 1;
        while (l < r) { int m = (l + r) >> 1; if (sse[m] <= i) l = m + 1; else r = m; }
        const int g = l - 1;
        segRow[t] = g;
        const int a = sse[g];
        relRow[t][0] = pos[2 * i + 0] - pos[2 * a + 0];
        relRow[t][1] = pos[2 * i + 1] - pos[2 * a + 1];
    }
    if (t >= BM && t < BM + 3) bnd[t - BM] = BM;
    for (int idx = t; idx < 4 * (BN + 4); idx += 256) ((int*)Pmax)[idx] = 0;
    __syncthreads();
    if (t < BM - 1) {
        const int s0 = segRow[t], s1 = segRow[t + 1];
        if (s1 != s0) bnd[s1 - segRow[0] - 1] = t + 1;   // <=3 boundaries in 128 rows (GROUP=50)
    }
    // (bnd consumed only after K-loop barriers)

    const int lane  = t & 63;
    const int wv    = t >> 6;
    const int wr    = (wv >> 1) * 64;
    const int wc    = (wv & 1) * 64;
    const int lcol  = lane & 15;
    const int lquad = lane >> 4;

    floatx4 acc[4][4];
#pragma unroll
    for (int m = 0; m < 4; ++m)
#pragma unroll
        for (int n = 0; n < 4; ++n) { acc[m][n] = (floatx4){0.f, 0.f, 0.f, 0.f}; }

    // ---- K loop ----
    for (int kt = 0; kt < KD / BK; ++kt) {
        const int k0 = kt * BK;

        float4 av[4];
        uint4  bv[2];
        if (k0 < H) {
#pragma unroll
            for (int i = 0; i < 4; ++i) {
                const int idx = i * 256 + t;
                const int row = idx >> 3, kq = (idx & 7) * 4;
                av[i] = *(const float4*)&hist_enc[(size_t)(rowBase + row) * H + k0 + kq];
            }
        } else {
#pragma unroll
            for (int i = 0; i < 4; ++i) {
                const int idx = i * 256 + t;
                const int row = idx >> 3, kq = (idx & 7) * 4;
                const int e   = k0 - H + kq;
                const float4 w0 = *(const float4*)&Ws[e];
                const float4 w1 = *(const float4*)&Ws[E + e];
                const float4 b4 = *(const float4*)&bs[e];
                const float r0 = relRow[row][0], r1 = relRow[row][1];
                av[i].x = fmaxf(r0 * w0.x + r1 * w1.x + b4.x, 0.f);
                av[i].y = fmaxf(r0 * w0.y + r1 * w1.y + b4.y, 0.f);
                av[i].z = fmaxf(r0 * w0.z + r1 * w1.z + b4.z, 0.f);
                av[i].w = fmaxf(r0 * w0.w + r1 * w1.w + b4.w, 0.f);
            }
        }
#pragma unroll
        for (int i = 0; i < 2; ++i) {
            const int idx = i * 256 + t;
            const int n = idx >> 2, q = idx & 3;
            bv[i] = *(const uint4*)&WmT[(size_t)(cTile + n) * KD + k0 + q * 8];
        }

        __syncthreads();   // previous tile fully consumed

#pragma unroll
        for (int i = 0; i < 4; ++i) {
            const int idx = i * 256 + t;
            const int row = idx >> 3, kq = (idx & 7) * 4;
            ushort4 p;
            p.x = f2bf(av[i].x); p.y = f2bf(av[i].y);
            p.z = f2bf(av[i].z); p.w = f2bf(av[i].w);
            *(ushort4*)&As[row][kq] = p;
        }
#pragma unroll
        for (int i = 0; i < 2; ++i) {
            const int idx = i * 256 + t;
            const int n = idx >> 2, q = idx & 3;
            *(uint4*)&Bs[n][q * 8] = bv[i];
        }

        __syncthreads();   // tiles visible

        bf16x8 af[4], bfr[4];
#pragma unroll
        for (int mt = 0; mt < 4; ++mt)
            af[mt] = *(const bf16x8*)&As[wr + mt * 16 + lcol][lquad * 8];
#pragma unroll
        for (int nt = 0; nt < 4; ++nt)
            bfr[nt] = *(const bf16x8*)&Bs[wc + nt * 16 + lcol][lquad * 8];
#pragma unroll
        for (int mt = 0; mt < 4; ++mt)
#pragma unroll
            for (int nt = 0; nt < 4; ++nt)
                acc[mt][nt] = __builtin_amdgcn_mfma_f32_16x16x32_bf16(af[mt], bfr[nt], acc[mt][nt], 0, 0, 0);
    }

    // ---- epilogue: bias + relu + segment-max ----
    const int b0 = bnd[0], b1 = bnd[1], b2 = bnd[2];
    const int segBase = segRow[0];

#pragma unroll
    for (int nt = 0; nt < 4; ++nt) {
        const int col  = wc + nt * 16 + lcol;
        const float bias = bm[cTile + col];
        float pm[4] = {0.f, 0.f, 0.f, 0.f};
#pragma unroll
        for (int mt = 0; mt < 4; ++mt) {
#pragma unroll
            for (int r = 0; r < 4; ++r) {
                const int lr = wr + mt * 16 + lquad * 4 + r;
                const int ls = (lr >= b0) + (lr >= b1) + (lr >= b2);
                float v = fmaxf(acc[mt][nt][r] + bias, 0.f);
                pm[ls] = fmaxf(pm[ls], v);
            }
        }
#pragma unroll
        for (int ls = 0; ls < 4; ++ls)
            if (pm[ls] > 0.f)
                atomicMax(&Pmax[ls][col], __float_as_int(pm[ls]));
    }
    __syncthreads();

    for (int idx = t; idx < 4 * BN; idx += 256) {
        const int ls = idx >> 7, col = idx & 127;
        if (ls > 0 && bnd[ls - 1] >= BM) continue;   // no such local segment
        const int seg = segBase + ls;
        const int v   = Pmax[ls][col];
        const int gs  = sse[seg], ge = sse[seg + 1];
        float* dst = &out[(size_t)seg * H + cTile + col];
        if (gs >= rowBase && ge <= rowBase + BM) {
            *dst = __int_as_float(v);                 // group fully inside this block: unique writer
        } else {
            atomicMax((int*)dst, v);                  // straddling group: combine across blocks
        }
    }
}

extern "C" void kernel_launch(void* const* d_in, const int* in_sizes, int n_in,
                              void* d_out, int out_size, void* d_ws, size_t ws_size,
                              hipStream_t stream) {
    const float* hist_enc = (const float*)d_in[0];
    const float* pos      = (const float*)d_in[1];
    const int*   sse      = (const int*)  d_in[2];
    const float* Ws       = (const float*)d_in[3];
    const float* bs       = (const float*)d_in[4];
    const float* Wm       = (const float*)d_in[5];
    const float* bm       = (const float*)d_in[6];
    float*       out      = (float*)d_out;
    unsigned short* WmT   = (unsigned short*)d_ws;   // 512*640*2 = 655,360 B

    hipMemsetAsync(out, 0, (size_t)out_size * sizeof(float), stream);
    wm_transpose<<<dim3(KD / 64, H / 64), 256, 0, stream>>>(Wm, WmT);
    pool_mfma<<<dim3(H / BN, NR / BM), 256, 0, stream>>>(hist_enc, pos, sse, Ws, bs, WmT, bm, out);
}

// Round 3
// 520.604 us; speedup vs baseline: 2.2433x; 1.0662x over previous
//
#include <hip/hip_runtime.h>

// PoolHiddenNet round 3: two-pass m97-style.
// Pass 0: WmT[n][k] = bf16(Wm[k][n])  (655 KB, L2/L3-resident).
// Pass 1: Abf[i][k] = bf16([hist_enc || emb])  (102400 x 640, 131 MB in d_ws).
// Pass 2: 128x128x32 bf16 MFMA GEMM with global_load_lds(16B) staging for A and B
//         (XOR-swizzled via the global source chunk so ds_read_b128 is ~2-way only),
//         fused bias+relu+segment-max epilogue.
// Fallback to round-2 single-pass kernel if ws_size can't hold Abf.

typedef __bf16 bf16x8 __attribute__((ext_vector_type(8)));
typedef float floatx4 __attribute__((ext_vector_type(4)));

constexpr int NR = 102400;
constexpr int NG = 2048;
constexpr int E  = 128;
constexpr int H  = 512;
constexpr int KD = 640;
constexpr int BM = 128, BN = 128, BK = 32;

__device__ inline unsigned short f2bf(float f) {
    unsigned u = __float_as_uint(f);
    u += 0x7FFF + ((u >> 16) & 1u);   // RNE (finite inputs)
    return (unsigned short)(u >> 16);
}

__device__ inline void async16(const unsigned short* g, unsigned short* l) {
    __builtin_amdgcn_global_load_lds(
        (const __attribute__((address_space(1))) unsigned int*)g,
        (__attribute__((address_space(3))) unsigned int*)l, 16, 0, 0);
}

// ---------------- pass 0: Wm (640,512) fp32 -> WmT (512,640) bf16 ----------------
__global__ __launch_bounds__(256) void wm_transpose(const float* __restrict__ Wm,
                                                    unsigned short* __restrict__ WmT) {
    __shared__ float tile[64][65];
    const int kb = blockIdx.x * 64, nb = blockIdx.y * 64;
    const int tx = threadIdx.x & 63, tq = threadIdx.x >> 6;
#pragma unroll
    for (int i = 0; i < 16; ++i) {
        const int k = tq * 16 + i;
        tile[k][tx] = Wm[(size_t)(kb + k) * H + nb + tx];
    }
    __syncthreads();
#pragma unroll
    for (int i = 0; i < 16; ++i) {
        const int n = tq * 16 + i;
        WmT[(size_t)(nb + n) * KD + kb + tx] = f2bf(tile[tx][n]);
    }
}

// ---------------- pass 1: build Abf (NR, 640) bf16 ----------------
__global__ __launch_bounds__(256) void build_a(
    const float* __restrict__ hist_enc, const float* __restrict__ pos,
    const int* __restrict__ sse, const float* __restrict__ Ws,
    const float* __restrict__ bs, unsigned short* __restrict__ Abf)
{
    __shared__ float relRow[BM][2];
    const int t = threadIdx.x;
    const int rowBase = blockIdx.x * BM;
    if (t < BM) {
        const int i = rowBase + t;
        int l = 0, r = NG + 1;
        while (l < r) { int m = (l + r) >> 1; if (sse[m] <= i) l = m + 1; else r = m; }
        const int a = sse[l - 1];
        relRow[t][0] = pos[2 * i + 0] - pos[2 * a + 0];
        relRow[t][1] = pos[2 * i + 1] - pos[2 * a + 1];
    }
    __syncthreads();
    // hist part: 128 rows x 512, 8-elem chunks
#pragma unroll 4
    for (int j = 0; j < 32; ++j) {
        const int c = j * 256 + t;
        const int row = c >> 6, col = (c & 63) * 8;
        const float4 f0 = *(const float4*)&hist_enc[(size_t)(rowBase + row) * H + col];
        const float4 f1 = *(const float4*)&hist_enc[(size_t)(rowBase + row) * H + col + 4];
        unsigned short ub[8] = {f2bf(f0.x), f2bf(f0.y), f2bf(f0.z), f2bf(f0.w),
                                f2bf(f1.x), f2bf(f1.y), f2bf(f1.z), f2bf(f1.w)};
        *(uint4*)&Abf[(size_t)(rowBase + row) * KD + col] = *(const uint4*)ub;
    }
    // emb part: 128 rows x 128
#pragma unroll 2
    for (int j = 0; j < 8; ++j) {
        const int c = j * 256 + t;
        const int row = c >> 4, e = (c & 15) * 8;
        const float r0 = relRow[row][0], r1 = relRow[row][1];
        const float4 w0a = *(const float4*)&Ws[e],     w0b = *(const float4*)&Ws[e + 4];
        const float4 w1a = *(const float4*)&Ws[E + e], w1b = *(const float4*)&Ws[E + e + 4];
        const float4 ba  = *(const float4*)&bs[e],     bb  = *(const float4*)&bs[e + 4];
        unsigned short ub[8] = {
            f2bf(fmaxf(r0 * w0a.x + r1 * w1a.x + ba.x, 0.f)),
            f2bf(fmaxf(r0 * w0a.y + r1 * w1a.y + ba.y, 0.f)),
            f2bf(fmaxf(r0 * w0a.z + r1 * w1a.z + ba.z, 0.f)),
            f2bf(fmaxf(r0 * w0a.w + r1 * w1a.w + ba.w, 0.f)),
            f2bf(fmaxf(r0 * w0b.x + r1 * w1b.x + bb.x, 0.f)),
            f2bf(fmaxf(r0 * w0b.y + r1 * w1b.y + bb.y, 0.f)),
            f2bf(fmaxf(r0 * w0b.z + r1 * w1b.z + bb.z, 0.f)),
            f2bf(fmaxf(r0 * w0b.w + r1 * w1b.w + bb.w, 0.f))};
        *(uint4*)&Abf[(size_t)(rowBase + row) * KD + H + e] = *(const uint4*)ub;
    }
}

// ---------------- pass 2: GEMM + segment-max ----------------
__global__ __launch_bounds__(256) void pool_mfma2(
    const unsigned short* __restrict__ Abf,   // (NR, 640) bf16
    const int*   __restrict__ sse,
    const unsigned short* __restrict__ WmT,   // (512, 640) bf16
    const float* __restrict__ bm,
    float*       __restrict__ out)            // (2048, 512) fp32, zeroed
{
    __shared__ __attribute__((aligned(16))) unsigned short As[BM * BK];  // 8 KB, swizzled
    __shared__ __attribute__((aligned(16))) unsigned short Bs[BN * BK];  // 8 KB, swizzled
    __shared__ int segRow[BM];
    __shared__ int bnd[3];
    __shared__ int Pmax[4][BN + 4];

    const int t       = threadIdx.x;
    const int cTile   = blockIdx.x * BN;
    const int rowBase = blockIdx.y * BM;

    if (t < BM) {
        const int i = rowBase + t;
        int l = 0, r = NG + 1;
        while (l < r) { int m = (l + r) >> 1; if (sse[m] <= i) l = m + 1; else r = m; }
        segRow[t] = l - 1;
    }
    if (t >= BM && t < BM + 3) bnd[t - BM] = BM;
    for (int idx = t; idx < 4 * (BN + 4); idx += 256) ((int*)Pmax)[idx] = 0;
    __syncthreads();
    if (t < BM - 1) {
        const int s0 = segRow[t], s1 = segRow[t + 1];
        if (s1 != s0) bnd[s1 - segRow[0] - 1] = t + 1;
    }

    const int lane  = t & 63;
    const int wv    = t >> 6;
    const int wr    = (wv >> 1) * 64;
    const int wc    = (wv & 1) * 64;
    const int lcol  = lane & 15;
    const int lquad = lane >> 4;

    // DMA staging: wave wv stages rows [wv*32, wv*32+32) of both tiles.
    // LDS slot (fixed by HW): base + lane*16. Logical (row, physChunk) = (seg*16 + lane>>2, lane&3).
    // Source chunk is XOR-swizzled so fragment reads land on distinct bank-quads.
    const int sRow0 = wv * 32 + (lane >> 2);
    const int sRow1 = sRow0 + 16;
    const int phys  = lane & 3;
    const int cl0   = phys ^ ((sRow0 >> 1) & 3);
    const int cl1   = phys ^ ((sRow1 >> 1) & 3);
    const unsigned short* gA0 = Abf + (size_t)(rowBase + sRow0) * KD + cl0 * 8;
    const unsigned short* gA1 = Abf + (size_t)(rowBase + sRow1) * KD + cl1 * 8;
    const unsigned short* gB0 = WmT + (size_t)(cTile + sRow0) * KD + cl0 * 8;
    const unsigned short* gB1 = WmT + (size_t)(cTile + sRow1) * KD + cl1 * 8;
    unsigned short* lA0 = &As[(wv * 2 + 0) * 512];
    unsigned short* lA1 = &As[(wv * 2 + 1) * 512];
    unsigned short* lB0 = &Bs[(wv * 2 + 0) * 512];
    unsigned short* lB1 = &Bs[(wv * 2 + 1) * 512];

    floatx4 acc[4][4];
#pragma unroll
    for (int m = 0; m < 4; ++m)
#pragma unroll
        for (int n = 0; n < 4; ++n) acc[m][n] = (floatx4){0.f, 0.f, 0.f, 0.f};

    for (int kt = 0; kt < KD / BK; ++kt) {
        const int ko = kt * BK;
        __syncthreads();            // previous tile fully consumed
        async16(gA0 + ko, lA0);
        async16(gA1 + ko, lA1);
        async16(gB0 + ko, lB0);
        async16(gB1 + ko, lB1);
        __syncthreads();            // vmcnt(0) drained before barrier -> tiles visible

        bf16x8 af[4], bfr[4];
#pragma unroll
        for (int mt = 0; mt < 4; ++mt) {
            const int R = wr + mt * 16 + lcol;
            const int pc = lquad ^ ((R >> 1) & 3);
            af[mt] = *(const bf16x8*)&As[R * 32 + pc * 8];
        }
#pragma unroll
        for (int nt = 0; nt < 4; ++nt) {
            const int R = wc + nt * 16 + lcol;
            const int pc = lquad ^ ((R >> 1) & 3);
            bfr[nt] = *(const bf16x8*)&Bs[R * 32 + pc * 8];
        }
#pragma unroll
        for (int mt = 0; mt < 4; ++mt)
#pragma unroll
            for (int nt = 0; nt < 4; ++nt)
                acc[mt][nt] = __builtin_amdgcn_mfma_f32_16x16x32_bf16(af[mt], bfr[nt], acc[mt][nt], 0, 0, 0);
    }

    // ---- epilogue: bias + relu + segment-max ----
    const int b0 = bnd[0], b1 = bnd[1], b2 = bnd[2];
    const int segBase = segRow[0];

#pragma unroll
    for (int nt = 0; nt < 4; ++nt) {
        const int col  = wc + nt * 16 + lcol;
        const float bias = bm[cTile + col];
        float pm[4] = {0.f, 0.f, 0.f, 0.f};
#pragma unroll
        for (int mt = 0; mt < 4; ++mt) {
#pragma unroll
            for (int r = 0; r < 4; ++r) {
                const int lr = wr + mt * 16 + lquad * 4 + r;
                const int ls = (lr >= b0) + (lr >= b1) + (lr >= b2);
                const float v = fmaxf(acc[mt][nt][r] + bias, 0.f);
                pm[ls] = fmaxf(pm[ls], v);
            }
        }
#pragma unroll
        for (int ls = 0; ls < 4; ++ls)
            if (pm[ls] > 0.f)
                atomicMax(&Pmax[ls][col], __float_as_int(pm[ls]));
    }
    __syncthreads();

    for (int idx = t; idx < 4 * BN; idx += 256) {
        const int ls = idx >> 7, col = idx & 127;
        if (ls > 0 && bnd[ls - 1] >= BM) continue;
        const int seg = segBase + ls;
        const int v   = Pmax[ls][col];
        const int gs  = sse[seg], ge = sse[seg + 1];
        float* dst = &out[(size_t)seg * H + cTile + col];
        if (gs >= rowBase && ge <= rowBase + BM) {
            *dst = __int_as_float(v);
        } else {
            atomicMax((int*)dst, v);
        }
    }
}

// ---------------- fallback (round-2 kernel, used when ws too small) ----------------
constexpr int LDAF = 40;
__global__ __launch_bounds__(256) void pool_mfma_fb(
    const float* __restrict__ hist_enc, const float* __restrict__ pos,
    const int* __restrict__ sse, const float* __restrict__ Ws,
    const float* __restrict__ bs, const unsigned short* __restrict__ WmT,
    const float* __restrict__ bm, float* __restrict__ out)
{
    __shared__ __attribute__((aligned(16))) unsigned short As[BM][LDAF];
    __shared__ __attribute__((aligned(16))) unsigned short Bs[BN][LDAF];
    __shared__ float relRow[BM][2];
    __shared__ int   segRow[BM];
    __shared__ int   bnd[3];
    __shared__ int   Pmax[4][BN + 4];

    const int t = threadIdx.x;
    const int cTile = blockIdx.x * BN;
    const int rowBase = blockIdx.y * BM;

    if (t < BM) {
        const int i = rowBase + t;
        int l = 0, r = NG + 1;
        while (l < r) { int m = (l + r) >> 1; if (sse[m] <= i) l = m + 1; else r = m; }
        const int g = l - 1;
        segRow[t] = g;
        const int a = sse[g];
        relRow[t][0] = pos[2 * i + 0] - pos[2 * a + 0];
        relRow[t][1] = pos[2 * i + 1] - pos[2 * a + 1];
    }
    if (t >= BM && t < BM + 3) bnd[t - BM] = BM;
    for (int idx = t; idx < 4 * (BN + 4); idx += 256) ((int*)Pmax)[idx] = 0;
    __syncthreads();
    if (t < BM - 1) {
        const int s0 = segRow[t], s1 = segRow[t + 1];
        if (s1 != s0) bnd[s1 - segRow[0] - 1] = t + 1;
    }

    const int lane = t & 63, wv = t >> 6;
    const int wr = (wv >> 1) * 64, wc = (wv & 1) * 64;
    const int lcol = lane & 15, lquad = lane >> 4;

    floatx4 acc[4][4];
#pragma unroll
    for (int m = 0; m < 4; ++m)
#pragma unroll
        for (int n = 0; n < 4; ++n) acc[m][n] = (floatx4){0.f, 0.f, 0.f, 0.f};

    for (int kt = 0; kt < KD / BK; ++kt) {
        const int k0 = kt * BK;
        float4 av[4]; uint4 bv[2];
        if (k0 < H) {
#pragma unroll
            for (int i = 0; i < 4; ++i) {
                const int idx = i * 256 + t;
                const int row = idx >> 3, kq = (idx & 7) * 4;
                av[i] = *(const float4*)&hist_enc[(size_t)(rowBase + row) * H + k0 + kq];
            }
        } else {
#pragma unroll
            for (int i = 0; i < 4; ++i) {
                const int idx = i * 256 + t;
                const int row = idx >> 3, kq = (idx & 7) * 4;
                const int e = k0 - H + kq;
                const float4 w0 = *(const float4*)&Ws[e];
                const float4 w1 = *(const float4*)&Ws[E + e];
                const float4 b4 = *(const float4*)&bs[e];
                const float r0 = relRow[row][0], r1 = relRow[row][1];
                av[i].x = fmaxf(r0 * w0.x + r1 * w1.x + b4.x, 0.f);
                av[i].y = fmaxf(r0 * w0.y + r1 * w1.y + b4.y, 0.f);
                av[i].z = fmaxf(r0 * w0.z + r1 * w1.z + b4.z, 0.f);
                av[i].w = fmaxf(r0 * w0.w + r1 * w1.w + b4.w, 0.f);
            }
        }
#pragma unroll
        for (int i = 0; i < 2; ++i) {
            const int idx = i * 256 + t;
            const int n = idx >> 2, q = idx & 3;
            bv[i] = *(const uint4*)&WmT[(size_t)(cTile + n) * KD + k0 + q * 8];
        }
        __syncthreads();
#pragma unroll
        for (int i = 0; i < 4; ++i) {
            const int idx = i * 256 + t;
            const int row = idx >> 3, kq = (idx & 7) * 4;
            ushort4 p;
            p.x = f2bf(av[i].x); p.y = f2bf(av[i].y);
            p.z = f2bf(av[i].z); p.w = f2bf(av[i].w);
            *(ushort4*)&As[row][kq] = p;
        }
#pragma unroll
        for (int i = 0; i < 2; ++i) {
            const int idx = i * 256 + t;
            const int n = idx >> 2, q = idx & 3;
            *(uint4*)&Bs[n][q * 8] = bv[i];
        }
        __syncthreads();

        bf16x8 af[4], bfr[4];
#pragma unroll
        for (int mt = 0; mt < 4; ++mt)
            af[mt] = *(const bf16x8*)&As[wr + mt * 16 + lcol][lquad * 8];
#pragma unroll
        for (int nt = 0; nt < 4; ++nt)
            bfr[nt] = *(const bf16x8*)&Bs[wc + nt * 16 + lcol][lquad * 8];
#pragma unroll
        for (int mt = 0; mt < 4; ++mt)
#pragma unroll
            for (int nt = 0; nt < 4; ++nt)
                acc[mt][nt] = __builtin_amdgcn_mfma_f32_16x16x32_bf16(af[mt], bfr[nt], acc[mt][nt], 0, 0, 0);
    }

    const int b0 = bnd[0], b1 = bnd[1], b2 = bnd[2];
    const int segBase = segRow[0];
#pragma unroll
    for (int nt = 0; nt < 4; ++nt) {
        const int col = wc + nt * 16 + lcol;
        const float bias = bm[cTile + col];
        float pm[4] = {0.f, 0.f, 0.f, 0.f};
#pragma unroll
        for (int mt = 0; mt < 4; ++mt) {
#pragma unroll
            for (int r = 0; r < 4; ++r) {
                const int lr = wr + mt * 16 + lquad * 4 + r;
                const int ls = (lr >= b0) + (lr >= b1) + (lr >= b2);
                const float v = fmaxf(acc[mt][nt][r] + bias, 0.f);
                pm[ls] = fmaxf(pm[ls], v);
            }
        }
#pragma unroll
        for (int ls = 0; ls < 4; ++ls)
            if (pm[ls] > 0.f) atomicMax(&Pmax[ls][col], __float_as_int(pm[ls]));
    }
    __syncthreads();
    for (int idx = t; idx < 4 * BN; idx += 256) {
        const int ls = idx >> 7, col = idx & 127;
        if (ls > 0 && bnd[ls - 1] >= BM) continue;
        const int seg = segBase + ls;
        const int v = Pmax[ls][col];
        const int gs = sse[seg], ge = sse[seg + 1];
        float* dst = &out[(size_t)seg * H + cTile + col];
        if (gs >= rowBase && ge <= rowBase + BM) *dst = __int_as_float(v);
        else atomicMax((int*)dst, v);
    }
}

extern "C" void kernel_launch(void* const* d_in, const int* in_sizes, int n_in,
                              void* d_out, int out_size, void* d_ws, size_t ws_size,
                              hipStream_t stream) {
    const float* hist_enc = (const float*)d_in[0];
    const float* pos      = (const float*)d_in[1];
    const int*   sse      = (const int*)  d_in[2];
    const float* Ws       = (const float*)d_in[3];
    const float* bs       = (const float*)d_in[4];
    const float* Wm       = (const float*)d_in[5];
    const float* bm       = (const float*)d_in[6];
    float*       out      = (float*)d_out;

    const size_t needWmT = (size_t)H * KD * 2;     // 655,360 B
    const size_t needA   = (size_t)NR * KD * 2;    // 131,072,000 B
    unsigned short* WmT  = (unsigned short*)d_ws;

    hipMemsetAsync(out, 0, (size_t)out_size * sizeof(float), stream);
    wm_transpose<<<dim3(KD / 64, H / 64), 256, 0, stream>>>(Wm, WmT);

    if (ws_size >= needWmT + needA) {
        unsigned short* Abf = (unsigned short*)((char*)d_ws + needWmT);
        build_a<<<NR / BM, 256, 0, stream>>>(hist_enc, pos, sse, Ws, bs, Abf);
        pool_mfma2<<<dim3(H / BN, NR / BM), 256, 0, stream>>>(Abf, sse, WmT, bm, out);
    } else {
        pool_mfma_fb<<<dim3(H / BN, NR / BM), 256, 0, stream>>>(hist_enc, pos, sse, Ws, bs, WmT, bm, out);
    }
}